// Round 4
// baseline (564.805 us; speedup 1.0000x reference)
//
#include <hip/hip_runtime.h>

// out[i, 0:48]  = x[i, :]
// out[i, 48:96] = sum over edges e with row[e]==i of x[col[e], :]
// x: [N, 48] f32, edge_index: [2, E] int32, out: [N, 96] f32
//
// Two-level scheme (round-4): coarse partition into 128-node buckets
// (tile-binned, run-contiguous writes -> low line amplification), then
// per-bucket LDS accumulation (ds_add_f32), single write per output row.
// Removes the fine CSR sort whose scattered 4B stores cost 106 MB of HBM
// writes (64B/line per edge) in round 3.

constexpr int D_IN  = 48;    // 12 float4
constexpr int D_OUT = 96;    // 24 float4
constexpr int BSH   = 7;     // 128 nodes per bucket
constexpr int BNODES = 1 << BSH;
constexpr int ACC_STRIDE = 49;  // odd (not ≡0 mod 4) -> LDS banks spread
constexpr int MAXNB = 1024;

constexpr int PT_THREADS = 256;
constexpr int PT_ITEMS   = 16;
constexpr int PT_TILE    = PT_THREADS * PT_ITEMS;  // 4096 edges per tile

// ---------------- coarse histogram ----------------

__global__ __launch_bounds__(PT_THREADS)
void coarse_hist_kernel(const int* __restrict__ row, int* __restrict__ gcount,
                        int n_edges, int nb) {
    __shared__ int h[MAXNB];
    for (int i = threadIdx.x; i < nb; i += PT_THREADS) h[i] = 0;
    __syncthreads();
    int base = blockIdx.x * PT_TILE;
#pragma unroll
    for (int j = 0; j < PT_ITEMS; ++j) {
        int e = base + j * PT_THREADS + threadIdx.x;
        if (e < n_edges) atomicAdd(&h[row[e] >> BSH], 1);
    }
    __syncthreads();
    for (int i = threadIdx.x; i < nb; i += PT_THREADS) {
        int c = h[i];
        if (c) atomicAdd(&gcount[i], c);
    }
}

// ---------------- scan of bucket counts (nb <= 1024, one block) ----------------
// gcursor may alias gcount (counts are read into LDS before any write).

__global__ __launch_bounds__(1024)
void coarse_scan_kernel(const int* __restrict__ gcount, int* __restrict__ pbase,
                        int* __restrict__ gcursor, int nb, int n_edges) {
    __shared__ int part[1024];
    int t = threadIdx.x;
    part[t] = (t < nb) ? gcount[t] : 0;
    __syncthreads();
    for (int off = 1; off < 1024; off <<= 1) {
        int v = (t >= off) ? part[t - off] : 0;
        __syncthreads();
        part[t] += v;
        __syncthreads();
    }
    if (t < nb) {
        int excl = (t == 0) ? 0 : part[t - 1];
        pbase[t] = excl;
        gcursor[t] = excl;
    }
    if (t == 0) pbase[nb] = n_edges;
}

// ---------------- tile-binned partition ----------------
// Packs each edge as (row & 127) << 17 | col  (col < 2^17).

__global__ __launch_bounds__(PT_THREADS)
void partition_kernel(const int* __restrict__ row, const int* __restrict__ col,
                      int* __restrict__ gcursor, unsigned int* __restrict__ pairs,
                      int n_edges, int nb) {
    __shared__ int hist[MAXNB];
    __shared__ int offs[MAXNB];
    __shared__ int gbase[MAXNB];
    __shared__ int scanbuf[PT_THREADS];

    int t = threadIdx.x;
    int tile0 = blockIdx.x * PT_TILE;

    for (int i = t; i < nb; i += PT_THREADS) hist[i] = 0;
    __syncthreads();

    int r[PT_ITEMS], c[PT_ITEMS];
#pragma unroll
    for (int j = 0; j < PT_ITEMS; ++j) {
        int e = tile0 + j * PT_THREADS + t;
        if (e < n_edges) {
            r[j] = row[e];
            c[j] = col[e];
            atomicAdd(&hist[r[j] >> BSH], 1);
        } else {
            r[j] = -1;
        }
    }
    __syncthreads();

    // block exclusive scan of hist[0..nb), 4 items per thread
    int cb = t * 4;
    int loc[4];
    int s = 0;
#pragma unroll
    for (int j = 0; j < 4; ++j) {
        int i = cb + j;
        loc[j] = (i < nb) ? hist[i] : 0;
        s += loc[j];
    }
    scanbuf[t] = s;
    __syncthreads();
    for (int off = 1; off < PT_THREADS; off <<= 1) {
        int v = (t >= off) ? scanbuf[t - off] : 0;
        __syncthreads();
        scanbuf[t] += v;
        __syncthreads();
    }
    int run = (t == 0) ? 0 : scanbuf[t - 1];
#pragma unroll
    for (int j = 0; j < 4; ++j) {
        int i = cb + j;
        if (i < nb) { offs[i] = run; run += loc[j]; }
    }
    // per-bucket global base (adjusted so global pos = gbase[b] + local_pos);
    // then reset hist to offs as the local cursor. Same thread owns hist[i],
    // offs[i] in both loops -> no barrier needed between them.
    for (int i = t; i < nb; i += PT_THREADS) {
        int cnt = hist[i];
        gbase[i] = cnt ? (atomicAdd(&gcursor[i], cnt) - offs[i]) : 0;
        hist[i] = offs[i];
    }
    __syncthreads();

#pragma unroll
    for (int j = 0; j < PT_ITEMS; ++j) {
        if (r[j] >= 0) {
            int b = r[j] >> BSH;
            int pos = atomicAdd(&hist[b], 1);
            pairs[gbase[b] + pos] =
                ((unsigned int)(r[j] & (BNODES - 1)) << 17) | (unsigned int)c[j];
        }
    }
}

// ---------------- per-bucket aggregation ----------------
// Block b owns nodes [b*128, b*128+128). 4 lanes per pair, each gathers
// 3 float4 (48B) of the x row and ds_add_f32's them into LDS accumulators.

__global__ __launch_bounds__(256)
void bucket_agg_kernel(const float4* __restrict__ x4,
                       const unsigned int* __restrict__ pairs,
                       const int* __restrict__ pbase,
                       float* __restrict__ out,
                       float4* __restrict__ out4,
                       int n_nodes) {
    __shared__ float acc[BNODES * ACC_STRIDE];
    __shared__ unsigned int stage[256];

    int t = threadIdx.x;
    int bkt = blockIdx.x;
    int nb0 = bkt << BSH;
    int ncnt = min(BNODES, n_nodes - nb0);

    for (int i = t; i < BNODES * ACC_STRIDE; i += 256) acc[i] = 0.f;
    __syncthreads();

    int p0 = pbase[bkt], p1 = pbase[bkt + 1];
    int g  = t >> 2;   // pair slot within staged chunk pass
    int qt = t & 3;    // quarter-row

    for (int chunk = p0; chunk < p1; chunk += 256) {
        int np = min(256, p1 - chunk);
        if (t < np) stage[t] = pairs[chunk + t];
        __syncthreads();
        int passes = (np + 63) >> 6;   // 64 pairs per pass
        for (int sp = 0; sp < passes; ++sp) {
            int pi = (sp << 6) + g;
            if (pi < np) {
                unsigned int pv = stage[pi];
                int rl = (int)(pv >> 17);
                int cc = (int)(pv & 0x1FFFFu);
                const float4* xr = &x4[(size_t)cc * 12 + qt * 3];
                float4 v0 = xr[0];
                float4 v1 = xr[1];
                float4 v2 = xr[2];
                float* arow = &acc[rl * ACC_STRIDE + qt * 12];
                atomicAdd(&arow[0],  v0.x); atomicAdd(&arow[1],  v0.y);
                atomicAdd(&arow[2],  v0.z); atomicAdd(&arow[3],  v0.w);
                atomicAdd(&arow[4],  v1.x); atomicAdd(&arow[5],  v1.y);
                atomicAdd(&arow[6],  v1.z); atomicAdd(&arow[7],  v1.w);
                atomicAdd(&arow[8],  v2.x); atomicAdd(&arow[9],  v2.y);
                atomicAdd(&arow[10], v2.z); atomicAdd(&arow[11], v2.w);
            }
        }
        __syncthreads();
    }

    // aggregated half: out[(nb0+n)*96 + 48 + d] = acc[n*49 + d]
    for (int idx = t; idx < ncnt * D_IN; idx += 256) {
        int n = idx / D_IN;
        int d = idx - n * D_IN;
        out[(size_t)(nb0 + n) * D_OUT + D_IN + d] = acc[n * ACC_STRIDE + d];
    }
    // copy half (float4)
    for (int idx = t; idx < ncnt * 12; idx += 256) {
        int n = idx / 12;
        int q = idx - n * 12;
        out4[(size_t)(nb0 + n) * 24 + q] = x4[(size_t)(nb0 + n) * 12 + q];
    }
}

// ---------------- fallback (round-1 atomic path) ----------------

__global__ void init_out_kernel(const float4* __restrict__ x4,
                                float4* __restrict__ out4, int n_nodes) {
    int idx = blockIdx.x * blockDim.x + threadIdx.x;
    int total = n_nodes * 24;
    if (idx >= total) return;
    int i = idx / 24;
    int q = idx - i * 24;
    out4[idx] = (q < 12) ? x4[i * 12 + q] : make_float4(0.f, 0.f, 0.f, 0.f);
}

__global__ void scatter_add_kernel(const float* __restrict__ x,
                                   const int* __restrict__ row,
                                   const int* __restrict__ col,
                                   float* __restrict__ out, int n_edges) {
    long long gid = (long long)blockIdx.x * blockDim.x + threadIdx.x;
    long long total = (long long)n_edges * D_IN;
    if (gid >= total) return;
    int e = (int)(gid / D_IN);
    int d = (int)(gid - (long long)e * D_IN);
    atomicAdd(out + (long long)row[e] * D_OUT + D_IN + d,
              x[(long long)col[e] * D_IN + d]);
}

// ---------------- launch ----------------

extern "C" void kernel_launch(void* const* d_in, const int* in_sizes, int n_in,
                              void* d_out, int out_size, void* d_ws, size_t ws_size,
                              hipStream_t stream) {
    const float* x  = (const float*)d_in[0];
    const int*   ei = (const int*)d_in[1];
    float*       out = (float*)d_out;

    int n_nodes = in_sizes[0] / D_IN;   // 100000
    int n_edges = in_sizes[1] / 2;      // 1600000
    const int* row = ei;
    const int* col = ei + n_edges;

    int nb = (n_nodes + BNODES - 1) >> BSH;              // 782
    int ntiles = (n_edges + PT_TILE - 1) / PT_TILE;      // 391

    // ws (ints): gcount/gcursor[nb] | pbase[nb+1] | pairs[E] (uint32)
    size_t needed = ((size_t)nb + (nb + 1) + n_edges) * sizeof(int);
    bool col_fits = n_nodes <= (1 << 17);

    if (ws_size < needed || nb > MAXNB || !col_fits) {
        int init_total = n_nodes * 24;
        init_out_kernel<<<(init_total + 255) / 256, 256, 0, stream>>>(
            (const float4*)x, (float4*)out, n_nodes);
        long long total = (long long)n_edges * D_IN;
        scatter_add_kernel<<<(int)((total + 255) / 256), 256, 0, stream>>>(
            x, row, col, out, n_edges);
        return;
    }

    int* gcount = (int*)d_ws;            // reused as gcursor after scan
    int* pbase  = gcount + nb;
    unsigned int* pairs = (unsigned int*)(pbase + nb + 1);

    hipMemsetAsync(gcount, 0, (size_t)nb * sizeof(int), stream);
    coarse_hist_kernel<<<ntiles, PT_THREADS, 0, stream>>>(row, gcount, n_edges, nb);
    coarse_scan_kernel<<<1, 1024, 0, stream>>>(gcount, pbase, gcount, nb, n_edges);
    partition_kernel<<<ntiles, PT_THREADS, 0, stream>>>(row, col, gcount, pairs,
                                                        n_edges, nb);
    bucket_agg_kernel<<<nb, 256, 0, stream>>>((const float4*)x, pairs, pbase,
                                              out, (float4*)out, n_nodes);
}

// Round 5
// 113.908 us; speedup vs baseline: 4.9584x; 4.9584x over previous
//
#include <hip/hip_runtime.h>

// out[i, 0:48]  = x[i, :]
// out[i, 48:96] = sum over edges e with row[e]==i of x[col[e], :]
// x: [N, 48] f32, edge_index: [2, E] int32, out: [N, 96] f32
//
// Round-5: keep coarse partition into 128-node buckets (proven ~47 us);
// replace the LDS-atomic consumer (517 us, latency-serialized) with a
// per-bucket counting sort + CSR register-accumulate aggregate:
//   4 threads/node own 12 floats each; inner gather loop has independent
//   iterations so multiple 192B x-row gathers stay in flight.

constexpr int D_IN  = 48;    // 12 float4
constexpr int D_OUT = 96;    // 24 float4
constexpr int BSH   = 7;     // 128 nodes per bucket
constexpr int BNODES = 1 << BSH;
constexpr int MAXNB = 1024;

constexpr int PT_THREADS = 256;
constexpr int PT_ITEMS   = 16;
constexpr int PT_TILE    = PT_THREADS * PT_ITEMS;  // 4096 edges per tile

constexpr int AG_THREADS = 512;                    // 4 threads per node
constexpr int CAP        = 3072;                   // pairs per chunk (mean ~2046)
constexpr int AG_ITEMS   = CAP / AG_THREADS;       // 6

// ---------------- coarse histogram ----------------

__global__ __launch_bounds__(PT_THREADS)
void coarse_hist_kernel(const int* __restrict__ row, int* __restrict__ gcount,
                        int n_edges, int nb) {
    __shared__ int h[MAXNB];
    for (int i = threadIdx.x; i < nb; i += PT_THREADS) h[i] = 0;
    __syncthreads();
    int base = blockIdx.x * PT_TILE;
#pragma unroll
    for (int j = 0; j < PT_ITEMS; ++j) {
        int e = base + j * PT_THREADS + threadIdx.x;
        if (e < n_edges) atomicAdd(&h[row[e] >> BSH], 1);
    }
    __syncthreads();
    for (int i = threadIdx.x; i < nb; i += PT_THREADS) {
        int c = h[i];
        if (c) atomicAdd(&gcount[i], c);
    }
}

// ---------------- scan of bucket counts (nb <= 1024, one block) ----------------

__global__ __launch_bounds__(1024)
void coarse_scan_kernel(const int* __restrict__ gcount, int* __restrict__ pbase,
                        int* __restrict__ gcursor, int nb, int n_edges) {
    __shared__ int part[1024];
    int t = threadIdx.x;
    part[t] = (t < nb) ? gcount[t] : 0;
    __syncthreads();
    for (int off = 1; off < 1024; off <<= 1) {
        int v = (t >= off) ? part[t - off] : 0;
        __syncthreads();
        part[t] += v;
        __syncthreads();
    }
    if (t < nb) {
        int excl = (t == 0) ? 0 : part[t - 1];
        pbase[t] = excl;
        gcursor[t] = excl;
    }
    if (t == 0) pbase[nb] = n_edges;
}

// ---------------- tile-binned partition ----------------
// Packs each edge as (row & 127) << 17 | col   (requires n_nodes <= 2^17).

__global__ __launch_bounds__(PT_THREADS)
void partition_kernel(const int* __restrict__ row, const int* __restrict__ col,
                      int* __restrict__ gcursor, unsigned int* __restrict__ pairs,
                      int n_edges, int nb) {
    __shared__ int hist[MAXNB];
    __shared__ int offs[MAXNB];
    __shared__ int gbase[MAXNB];
    __shared__ int scanbuf[PT_THREADS];

    int t = threadIdx.x;
    int tile0 = blockIdx.x * PT_TILE;

    for (int i = t; i < nb; i += PT_THREADS) hist[i] = 0;
    __syncthreads();

    int r[PT_ITEMS], c[PT_ITEMS];
#pragma unroll
    for (int j = 0; j < PT_ITEMS; ++j) {
        int e = tile0 + j * PT_THREADS + t;
        if (e < n_edges) {
            r[j] = row[e];
            c[j] = col[e];
            atomicAdd(&hist[r[j] >> BSH], 1);
        } else {
            r[j] = -1;
        }
    }
    __syncthreads();

    // block exclusive scan of hist[0..nb), 4 items per thread
    int cb = t * 4;
    int loc[4];
    int s = 0;
#pragma unroll
    for (int j = 0; j < 4; ++j) {
        int i = cb + j;
        loc[j] = (i < nb) ? hist[i] : 0;
        s += loc[j];
    }
    scanbuf[t] = s;
    __syncthreads();
    for (int off = 1; off < PT_THREADS; off <<= 1) {
        int v = (t >= off) ? scanbuf[t - off] : 0;
        __syncthreads();
        scanbuf[t] += v;
        __syncthreads();
    }
    int run = (t == 0) ? 0 : scanbuf[t - 1];
#pragma unroll
    for (int j = 0; j < 4; ++j) {
        int i = cb + j;
        if (i < nb) { offs[i] = run; run += loc[j]; }
    }
    for (int i = t; i < nb; i += PT_THREADS) {
        int cnt = hist[i];
        gbase[i] = cnt ? (atomicAdd(&gcursor[i], cnt) - offs[i]) : 0;
        hist[i] = offs[i];   // becomes local cursor
    }
    __syncthreads();

#pragma unroll
    for (int j = 0; j < PT_ITEMS; ++j) {
        if (r[j] >= 0) {
            int b = r[j] >> BSH;
            int pos = atomicAdd(&hist[b], 1);
            pairs[gbase[b] + pos] =
                ((unsigned int)(r[j] & (BNODES - 1)) << 17) | (unsigned int)c[j];
        }
    }
}

// ---------------- per-bucket counting sort + CSR aggregate ----------------

__device__ __forceinline__ void add4(float4& a, const float4& b) {
    a.x += b.x; a.y += b.y; a.z += b.z; a.w += b.w;
}

__global__ __launch_bounds__(AG_THREADS)
void bucket_sort_agg_kernel(const float4* __restrict__ x4,
                            const unsigned int* __restrict__ pairs,
                            const int* __restrict__ pbase,
                            float4* __restrict__ out4,
                            int n_nodes) {
    __shared__ unsigned int scol[CAP];   // sorted cols (17-bit values)
    __shared__ int hist[BNODES];
    __shared__ int offs[BNODES];
    __shared__ int cur[BNODES];
    __shared__ int hs[BNODES];

    int t   = threadIdx.x;
    int bkt = blockIdx.x;
    int nb0 = bkt << BSH;

    int p0 = pbase[bkt], p1 = pbase[bkt + 1];

    int n  = t >> 2;     // node 0..127
    int qt = t & 3;      // quarter-row: 3 float4 each
    float4 a0 = make_float4(0.f, 0.f, 0.f, 0.f);
    float4 a1 = make_float4(0.f, 0.f, 0.f, 0.f);
    float4 a2 = make_float4(0.f, 0.f, 0.f, 0.f);

    for (int base = p0; base < p1; base += CAP) {
        int cnt = min(CAP, p1 - base);

        if (t < BNODES) hist[t] = 0;
        __syncthreads();

        // load chunk into registers + LDS histogram
        unsigned int pv[AG_ITEMS];
#pragma unroll
        for (int j = 0; j < AG_ITEMS; ++j) {
            int idx = t + j * AG_THREADS;
            if (idx < cnt) {
                pv[j] = pairs[base + idx];
                atomicAdd(&hist[pv[j] >> 17], 1);
            }
        }
        __syncthreads();

        // exclusive scan of 128 bins (Hillis-Steele; all threads hit barriers)
        if (t < BNODES) hs[t] = hist[t];
        __syncthreads();
        for (int off = 1; off < BNODES; off <<= 1) {
            int v = (t >= off && t < BNODES) ? hs[t - off] : 0;
            __syncthreads();
            if (t < BNODES) hs[t] += v;
            __syncthreads();
        }
        if (t < BNODES) {
            int excl = hs[t] - hist[t];
            offs[t] = excl;
            cur[t]  = excl;
        }
        __syncthreads();

        // place into node order
#pragma unroll
        for (int j = 0; j < AG_ITEMS; ++j) {
            int idx = t + j * AG_THREADS;
            if (idx < cnt) {
                int bin = pv[j] >> 17;
                int pos = atomicAdd(&cur[bin], 1);
                scol[pos] = pv[j] & 0x1FFFFu;
            }
        }
        __syncthreads();

        // CSR aggregate: 4 threads per node, register accumulators.
        // Iterations independent -> multiple gathers in flight.
        int k0 = offs[n];
        int k1 = k0 + hist[n];
        for (int k = k0; k < k1; ++k) {
            size_t cbase = (size_t)scol[k] * 12 + qt * 3;
            float4 v0 = x4[cbase + 0];
            float4 v1 = x4[cbase + 1];
            float4 v2 = x4[cbase + 2];
            add4(a0, v0); add4(a1, v1); add4(a2, v2);
        }
        __syncthreads();   // protect scol/hist reuse next chunk
    }

    // single write per output row + fused x copy
    int node = nb0 + n;
    if (node < n_nodes) {
        size_t ob = (size_t)node * 24;
        size_t xb = (size_t)node * 12;
        out4[ob + 12 + qt * 3 + 0] = a0;
        out4[ob + 12 + qt * 3 + 1] = a1;
        out4[ob + 12 + qt * 3 + 2] = a2;
        out4[ob + qt * 3 + 0] = x4[xb + qt * 3 + 0];
        out4[ob + qt * 3 + 1] = x4[xb + qt * 3 + 1];
        out4[ob + qt * 3 + 2] = x4[xb + qt * 3 + 2];
    }
}

// ---------------- fallback (round-1 atomic path) ----------------

__global__ void init_out_kernel(const float4* __restrict__ x4,
                                float4* __restrict__ out4, int n_nodes) {
    int idx = blockIdx.x * blockDim.x + threadIdx.x;
    int total = n_nodes * 24;
    if (idx >= total) return;
    int i = idx / 24;
    int q = idx - i * 24;
    out4[idx] = (q < 12) ? x4[i * 12 + q] : make_float4(0.f, 0.f, 0.f, 0.f);
}

__global__ void scatter_add_kernel(const float* __restrict__ x,
                                   const int* __restrict__ row,
                                   const int* __restrict__ col,
                                   float* __restrict__ out, int n_edges) {
    long long gid = (long long)blockIdx.x * blockDim.x + threadIdx.x;
    long long total = (long long)n_edges * D_IN;
    if (gid >= total) return;
    int e = (int)(gid / D_IN);
    int d = (int)(gid - (long long)e * D_IN);
    atomicAdd(out + (long long)row[e] * D_OUT + D_IN + d,
              x[(long long)col[e] * D_IN + d]);
}

// ---------------- launch ----------------

extern "C" void kernel_launch(void* const* d_in, const int* in_sizes, int n_in,
                              void* d_out, int out_size, void* d_ws, size_t ws_size,
                              hipStream_t stream) {
    const float* x  = (const float*)d_in[0];
    const int*   ei = (const int*)d_in[1];
    float*       out = (float*)d_out;

    int n_nodes = in_sizes[0] / D_IN;   // 100000
    int n_edges = in_sizes[1] / 2;      // 1600000
    const int* row = ei;
    const int* col = ei + n_edges;

    int nb = (n_nodes + BNODES - 1) >> BSH;              // 782
    int ntiles = (n_edges + PT_TILE - 1) / PT_TILE;      // 391

    // ws (ints): gcount/gcursor[nb] | pbase[nb+1] | pairs[E] (uint32)
    size_t needed = ((size_t)nb + (nb + 1) + n_edges) * sizeof(int);
    bool col_fits = n_nodes <= (1 << 17);

    if (ws_size < needed || nb > MAXNB || !col_fits) {
        int init_total = n_nodes * 24;
        init_out_kernel<<<(init_total + 255) / 256, 256, 0, stream>>>(
            (const float4*)x, (float4*)out, n_nodes);
        long long total = (long long)n_edges * D_IN;
        scatter_add_kernel<<<(int)((total + 255) / 256), 256, 0, stream>>>(
            x, row, col, out, n_edges);
        return;
    }

    int* gcount = (int*)d_ws;            // reused as gcursor after scan
    int* pbase  = gcount + nb;
    unsigned int* pairs = (unsigned int*)(pbase + nb + 1);

    hipMemsetAsync(gcount, 0, (size_t)nb * sizeof(int), stream);
    coarse_hist_kernel<<<ntiles, PT_THREADS, 0, stream>>>(row, gcount, n_edges, nb);
    coarse_scan_kernel<<<1, 1024, 0, stream>>>(gcount, pbase, gcount, nb, n_edges);
    partition_kernel<<<ntiles, PT_THREADS, 0, stream>>>(row, col, gcount, pairs,
                                                        n_edges, nb);
    bucket_sort_agg_kernel<<<nb, AG_THREADS, 0, stream>>>(
        (const float4*)x, pairs, pbase, (float4*)out, n_nodes);
}